// Round 12
// baseline (45.500 us; speedup 1.0000x reference)
//
#include <hip/hip_runtime.h>

// Barnes-Wall Lambda16 quantizer — max-DP pass-1 + merged-emit pass-2.
//
// Pass 1 (surrogate, fully unrolled, zero memory ops, ~20 ops/candidate):
//   RM(1,4): O(k)_j = k0 XOR <kappa, pt_j>, kappa = k>>1, pt_j = column
//   points (bijection onto F2^4).
//   ssum(k): WHT (R11-validated): s = k0 ? S1 - h[kappa] : S0 + h[kappa].
//   mx(k) = max_j |d_sel|: butterfly max-DP over (T,S) pairs
//     (T[p],T[p|h],S[p],S[p|h]) <- (max(T,T'),max(T,S'),max(S,S'),max(S,T'))
//   4 stages x 8 butterflies x 4 = 128 v_max; mx(2kap)=T[kap],
//   mx(2kap+1)=S[kap]. f32 max is assoc/comm => bit-identical to R11's
//   per-k tree (same multiset).
//   parity: PAR32 word, bit k = (popcount((P1&O)|(P0&~O))+par2(k))&1.
//   Identity: sel_j = P0_j ^ (O_j & Q_j), Q = P0^P1; AND distributes over
//   XOR => parity(Q&O(k)) = XOR_{k-bits} parity(Q&Row_i). Build once
//   (~30 ops), per-k = bfe. Provably == R5..R11-validated formula.
//   Dtil = s + par*(1-2mx); stable top-3 (strict <, earlier k wins ties).
//
// Pass 2 (bit-exact numpy pipeline, R2..R11-verified semantics):
//   xh stashed to LDS (stride-17, 2-way conflict ~ free) instead of
//   reload+re-divide. eval_k always emits y; running ybest via cndmask
//   (R4-proven shape) replaces the final re-eval. Winner by lexicographic
//   (D,k) == numpy first-min.
//
// Pass-2 bit-exactness invariants (absmax must be 0.0):
//  - fp contract OFF; fmaf only where exact or single-rounding-identical:
//    fmaf(c,-0.5,xh) == fl(xh-c/2); fmaf(2,f,c) exact; Xp=fmaf(bit,+-2,X)
//    exact; e = fmaf(-2,xh,Xp) == fl(Xp-x) single rounding (x=2*xh exact).
//  - rintf == round-half-to-even == np.round; dd = x2 - f exact.
//  - first-max: contiguous-pair tournament, left wins ties (>=).
//  - parity (pass-2): float sum-tree of integer-valued f (exact), cvt, &1.
//  - D in numpy's n=16 pairwise order:
//    r[j]=sq[j]+sq[j+8]; D=((r0+r1)+(r2+r3))+((r4+r5)+(r6+r7)).
//
// Register discipline: pass-1 persistent = T[16]+S[16]+h[16]+S0,S1+PAR+
// top3 ~ 57 (== R11 envelope; T/S replace dd0/dd1). Gate counters:
// WRITE_SIZE ~<= 24 MB, FETCH ~ 8.5 MB (no scratch).

constexpr int G5[5][16] = {
    {1,1,1,1,0,1,0,1,1,0,0,1,0,0,0,0},
    {0,1,1,1,1,0,1,0,1,1,0,0,1,0,0,0},
    {0,0,1,1,1,1,0,1,0,1,1,0,0,1,0,0},
    {0,0,0,1,1,1,1,0,1,0,1,1,0,0,1,0},
    {1,1,1,1,1,1,1,1,1,1,1,1,1,1,1,1}};

struct Tabs {
  int m[16];        // column bit-masks: c_j(k) = popcount(k & m[j])
  int pt[16];       // pt[j] = 4-bit point (rows 0..3 at column j), bijective
  unsigned rowm[5]; // Row_i as bitmask over j
  unsigned par2w;   // bit k = par2(k) = XOR_j (c_j(k)>>1)&1
};
constexpr Tabs make_tabs() {
  Tabs t{};
  for (int j = 0; j < 16; ++j) {
    int m = 0;
    for (int i = 0; i < 5; ++i) m |= G5[i][j] << (4 - i);
    t.m[j] = m;
    t.pt[j] = (G5[0][j] << 3) | (G5[1][j] << 2) | (G5[2][j] << 1) | G5[3][j];
  }
  for (int i = 0; i < 5; ++i) {
    unsigned rm = 0;
    for (int j = 0; j < 16; ++j) rm |= (unsigned)G5[i][j] << j;
    t.rowm[i] = rm;
  }
  t.par2w = 0;
  for (int k = 0; k < 32; ++k) {
    unsigned p2 = 0;
    for (int j = 0; j < 16; ++j) {
      int c = 0;
      for (int i = 0; i < 5; ++i) c += ((k >> (4 - i)) & 1) * G5[i][j];
      p2 ^= (unsigned)((c >> 1) & 1);
    }
    t.par2w |= p2 << k;
  }
  return t;
}
constexpr Tabs tb = make_tabs();

__device__ __forceinline__ int parity16i(const float (&f)[16]) {
  // exact: all addends are small integers
  float s0 = ((f[0] + f[1]) + (f[2] + f[3])) + ((f[4] + f[5]) + (f[6] + f[7]));
  float s1 = ((f[8] + f[9]) + (f[10] + f[11])) + ((f[12] + f[13]) + (f[14] + f[15]));
  return ((int)(s0 + s1)) & 1;
}

// Exact numpy-pipeline evaluation of candidate kk (R2..R11-verified).
// Codeword row from LDS; always emits y (scaled candidate).
__device__ __forceinline__ float eval_k(int kk, const float (&xh)[16], float a,
                                        float (&y)[16], const float (*Cs)[16]) {
#pragma clang fp contract(off)
  float cf[16];
  {
    const float4* crow = reinterpret_cast<const float4*>(&Cs[kk][0]);
    float4 c0 = crow[0], c1 = crow[1], c2 = crow[2], c3 = crow[3];
    cf[0] = c0.x; cf[1] = c0.y; cf[2] = c0.z; cf[3] = c0.w;
    cf[4] = c1.x; cf[5] = c1.y; cf[6] = c1.z; cf[7] = c1.w;
    cf[8] = c2.x; cf[9] = c2.y; cf[10] = c2.z; cf[11] = c2.w;
    cf[12] = c3.x; cf[13] = c3.y; cf[14] = c3.z; cf[15] = c3.w;
  }
  float f[16], dd[16];
#pragma unroll
  for (int j = 0; j < 16; ++j) {
    float x2 = __builtin_fmaf(cf[j], -0.5f, xh[j]);  // == fl(xh - c/2)
    float fj = __builtin_rintf(x2);
    f[j] = fj;
    dd[j] = x2 - fj;                                 // exact
  }
  const int par = parity16i(f);

  // first-occurrence argmax of |dd| -> onehot (left wins ties)
  float tv[16];
  int ti[16];
#pragma unroll
  for (int j = 0; j < 16; ++j) { tv[j] = __builtin_fabsf(dd[j]); ti[j] = 1 << j; }
#pragma unroll
  for (int w = 8; w >= 1; w >>= 1) {
#pragma unroll
    for (int j = 0; j < w; ++j) {
      bool L = tv[2 * j] >= tv[2 * j + 1];
      tv[j] = L ? tv[2 * j] : tv[2 * j + 1];
      ti[j] = L ? ti[2 * j] : ti[2 * j + 1];
    }
  }
  const int ohm = par ? ti[0] : 0;   // patch mask (0 when parity even)

  float sq[16];
#pragma unroll
  for (int j = 0; j < 16; ++j) {
    float X  = __builtin_fmaf(2.0f, f[j], cf[j]);      // exact int
    float s2 = __builtin_copysignf(2.0f, dd[j]);       // corr direction
    float bitf = (float)((ohm >> j) & 1);
    float Xp = __builtin_fmaf(bitf, s2, X);            // exact int
    float e  = __builtin_fmaf(-2.0f, xh[j], Xp);       // == fl(Xp - x)
    sq[j] = e * e;
    y[j] = Xp * a;
  }
  float r0 = sq[0] + sq[8],  r1 = sq[1] + sq[9];
  float r2 = sq[2] + sq[10], r3 = sq[3] + sq[11];
  float r4 = sq[4] + sq[12], r5 = sq[5] + sq[13];
  float r6 = sq[6] + sq[14], r7 = sq[7] + sq[15];
  return ((r0 + r1) + (r2 + r3)) + ((r4 + r5) + (r6 + r7));
}

__global__ __launch_bounds__(256, 4) void bw_quant_kernel(
    const float* __restrict__ x_in,
    const float* __restrict__ C_rep,   // unused (constexpr codebook)
    const float* __restrict__ a_ptr,
    float* __restrict__ y_out,
    int n_rows)
{
#pragma clang fp contract(off)
  __shared__ alignas(16) float Cs[32][16];
  __shared__ float XH[256][17];        // stride 17: 2-way bank conflict ~free
  for (int i = threadIdx.x; i < 32 * 16; i += 256)
    Cs[i >> 4][i & 15] = (float)__builtin_popcount((i >> 4) & tb.m[i & 15]);
  __syncthreads();

  const int row = blockIdx.x * 256 + threadIdx.x;
  if (row >= n_rows) return;

  const float a = a_ptr[0];
  const int tid = threadIdx.x;

  // -------- prologue: residuals, parity masks, WHT inputs, xh stash -------
  float g[16], sq0[16], T[16], S[16];
  int P0 = 0, P1 = 0;
  {
    const float4* xr4 = reinterpret_cast<const float4*>(x_in + (size_t)row * 16);
    float xv[16];
#pragma unroll
    for (int q = 0; q < 4; ++q) {
      float4 v = xr4[q];
      xv[q * 4 + 0] = v.x; xv[q * 4 + 1] = v.y;
      xv[q * 4 + 2] = v.z; xv[q * 4 + 3] = v.w;
    }
#pragma unroll
    for (int j = 0; j < 16; ++j) {
      float xj = xv[j] / a;
      float xh = xj * 0.5f;                 // exact
      XH[tid][j] = xh;                      // stash for pass-2
      float t0 = __builtin_rintf(xh);
      float d0 = xh - t0;                   // exact
      float hm = xh - 0.5f;
      float t1 = __builtin_rintf(hm);
      float d1 = hm - t1;                   // exact
      P0 |= ((int)t0 & 1) << j;
      P1 |= ((int)t1 & 1) << j;
      sq0[j] = d0 * d0;
      g[tb.pt[j]] = __builtin_fmaf(d1, d1, -sq0[j]);  // delta by point
      T[tb.pt[j]] = __builtin_fabsf(d0);              // u by point
      S[tb.pt[j]] = __builtin_fabsf(d1);              // w by point
    }
  }
  float S0 = (((sq0[0] + sq0[1]) + (sq0[2] + sq0[3])) + ((sq0[4] + sq0[5]) + (sq0[6] + sq0[7])))
           + (((sq0[8] + sq0[9]) + (sq0[10] + sq0[11])) + ((sq0[12] + sq0[13]) + (sq0[14] + sq0[15])));

  // fast WHT on g (ssum path, R11-validated)
#pragma unroll
  for (int st = 1; st < 16; st <<= 1) {
#pragma unroll
    for (int p = 0; p < 16; ++p) {
      if (!(p & st)) {
        float u = g[p], v = g[p | st];
        g[p] = u + v;
        g[p | st] = u - v;
      }
    }
  }
  float S1 = S0 + g[0];
  float h[16];
  h[0] = 0.0f;
#pragma unroll
  for (int t = 1; t < 16; ++t) h[t] = 0.5f * (g[0] - g[t]);

  // butterfly max-DP: T[kap]=mx(2kap), S[kap]=mx(2kap+1) after 4 stages
#pragma unroll
  for (int st = 1; st < 16; st <<= 1) {
#pragma unroll
    for (int p = 0; p < 16; ++p) {
      if (!(p & st)) {
        float tA = T[p], tB = T[p | st];
        float sA = S[p], sB = S[p | st];
        T[p]      = __builtin_fmaxf(tA, tB);
        T[p | st] = __builtin_fmaxf(tA, sB);
        S[p]      = __builtin_fmaxf(sA, sB);
        S[p | st] = __builtin_fmaxf(sA, tB);
      }
    }
  }

  // PAR32: bit k = surrogate parity of candidate k (GF2-exact rewrite of
  // the validated popcount formula)
  unsigned PAR;
  {
    unsigned Q = (unsigned)(P0 ^ P1);
    PAR = ((__builtin_popcount((unsigned)P0) & 1) ? 0xFFFFFFFFu : 0u) ^ tb.par2w;
    PAR ^= ((__builtin_popcount(Q & tb.rowm[0]) & 1) ? 0xFFFF0000u : 0u);  // k bit 4
    PAR ^= ((__builtin_popcount(Q & tb.rowm[1]) & 1) ? 0xFF00FF00u : 0u);  // k bit 3
    PAR ^= ((__builtin_popcount(Q & tb.rowm[2]) & 1) ? 0xF0F0F0F0u : 0u);  // k bit 2
    PAR ^= ((__builtin_popcount(Q & tb.rowm[3]) & 1) ? 0xCCCCCCCCu : 0u);  // k bit 1
    PAR ^= ((__builtin_popcount(Q & tb.rowm[4]) & 1) ? 0xAAAAAAAAu : 0u);  // k bit 0
  }

  // -------- pass 1: fully unrolled surrogate ranking, stable top-3 --------
  float b1 = __builtin_inff(), b2 = b1, b3 = b1;
  int k1 = 0, k2 = 0, k3 = 0;

#pragma unroll
  for (int k = 0; k < 32; ++k) {
    const int kap = k >> 1;
    float s  = (k & 1) ? (S1 - h[kap]) : (S0 + h[kap]);   // WHT ssum
    float mx = (k & 1) ? S[kap] : T[kap];                 // DP max (register)
    float spen = s + __builtin_fmaf(-2.0f, mx, 1.0f);
    float dtil = ((PAR >> k) & 1u) ? spen : s;

    // stable top-3 insert (strict <: earlier k wins ties)
    bool lt1 = dtil < b1, lt2 = dtil < b2, lt3 = dtil < b3;
    float nb3 = lt3 ? (lt2 ? b2 : dtil) : b3;  int nk3 = lt3 ? (lt2 ? k2 : k) : k3;
    float nb2 = lt2 ? (lt1 ? b1 : dtil) : b2;  int nk2 = lt2 ? (lt1 ? k1 : k) : k2;
    b3 = nb3; k3 = nk3;
    b2 = nb2; k2 = nk2;
    b1 = lt1 ? dtil : b1;  k1 = lt1 ? k : k1;
  }

  // -------- pass 2: exact evals with running winner (merged emit) ---------
  float xh[16];
#pragma unroll
  for (int j = 0; j < 16; ++j) xh[j] = XH[tid][j];

  float yb[16], yt[16];
  float Db = eval_k(k1, xh, a, yb, Cs);
  int kb = k1;
  {
    float D2 = eval_k(k2, xh, a, yt, Cs);
    bool c2 = (D2 < Db) || (D2 == Db && k2 < kb);
    Db = c2 ? D2 : Db; kb = c2 ? k2 : kb;
#pragma unroll
    for (int j = 0; j < 16; ++j) yb[j] = c2 ? yt[j] : yb[j];
  }
  {
    float D3 = eval_k(k3, xh, a, yt, Cs);
    bool c3 = (D3 < Db) || (D3 == Db && k3 < kb);
#pragma unroll
    for (int j = 0; j < 16; ++j) yb[j] = c3 ? yt[j] : yb[j];
  }

  float4* yr4 = reinterpret_cast<float4*>(y_out + (size_t)row * 16);
#pragma unroll
  for (int q = 0; q < 4; ++q) {
    float4 v;
    v.x = yb[q * 4 + 0]; v.y = yb[q * 4 + 1];
    v.z = yb[q * 4 + 2]; v.w = yb[q * 4 + 3];
    yr4[q] = v;
  }
}

extern "C" void kernel_launch(void* const* d_in, const int* in_sizes, int n_in,
                              void* d_out, int out_size, void* d_ws, size_t ws_size,
                              hipStream_t stream) {
  const float* x_in  = (const float*)d_in[0];
  const float* C_rep = (const float*)d_in[1];
  const float* a_ptr = (const float*)d_in[2];
  float* y_out = (float*)d_out;

  const int n_rows = in_sizes[0] / 16;
  const int block = 256;
  const int grid = (n_rows + block - 1) / block;
  bw_quant_kernel<<<grid, block, 0, stream>>>(x_in, C_rep, a_ptr, y_out, n_rows);
}

// Round 13
// 44.176 us; speedup vs baseline: 1.0300x; 1.0300x over previous
//
#include <hip/hip_runtime.h>

// Barnes-Wall Lambda16 quantizer — pair-split (2 threads/row), take 2.
//
// R9 retry with the ONE change: __launch_bounds__(256, 4) instead of (256,8).
// Empirical allocator rule (R3/R5/R9/R12): under (256,N) the backend targets
// ~256/N VGPRs and spills to hit it. (256,8) squeezed R9's ~55-reg working
// set into 32 VGPRs -> 260MB scratch traffic. (256,4) targets 64 = exactly
// the 8-waves/SIMD occupancy cliff (m69) -> pair-split's 8192 waves can
// co-reside (8 blocks/CU at VGPR=64, LDS 512B; launch_bounds is an
// allocation hint, not an HW occupancy cap).
//
// Structure (R9, passed absmax 0.0):
//  - pass-1: each thread ranks 16 of 32 candidates (surrogate Dtil,
//    R5..R12-validated math), stable local top-3.
//  - merge: 6 shfl_xor + 3 stable inserts => exact global (dtil,k)-lex top-3
//    (all hi-half k > all lo-half k, so strict-< insert == lex merge).
//  - pass-2: t0 evals k1, t1 evals k2, both eval k3; 1 shuffle shares D's;
//    winner by lexicographic (D,k) == numpy first-min.
//  - emit: both lanes run eval_k<true>(kb); each stores its 32B half-row.
//
// Pass-1 surrogate (validated absmax 0.0 in R5..R12):
//   dd0[j] = xh - rint(xh); dd1[j] = (xh-.5) - rint(xh-.5)  (mod-2 tables)
//   Dtil = sum d^2 + par * (1 - 2*max|d|)   ( = D_k/4 in reals )
//   par = (popcount((P1&O)|(P0&~O)) + par2(k)) & 1
//
// Pass-2 bit-exactness invariants (absmax must be 0.0):
//  - fp contract OFF; fmaf only where exact or single-rounding-identical:
//    fmaf(c,-0.5,xh) == fl(xh-c/2) == fl(fl(x-c)*0.5); fmaf(2,f,c) exact;
//    Xp = fmaf(bit,+-2,X) exact (integers).
//  - rintf == round-half-to-even == np.round; dd = x2 - f exact.
//  - first-max: contiguous-pair tournament, left wins ties (>=).
//  - corr = f + sign(dd) == ceil(xc)+floor(xc)-fc (incl. exact halves).
//  - e = Xp - x directly (single rounding); D in numpy's n=16 pairwise
//    order: r[j]=sq[j]+sq[j+8]; D=((r0+r1)+(r2+r3))+((r4+r5)+(r6+r7)).
//  - parity (pass-2): float sum-tree of integer-valued f (exact), cvt, &1.

constexpr int G5[5][16] = {
    {1,1,1,1,0,1,0,1,1,0,0,1,0,0,0,0},
    {0,1,1,1,1,0,1,0,1,1,0,0,1,0,0,0},
    {0,0,1,1,1,1,0,1,0,1,1,0,0,1,0,0},
    {0,0,0,1,1,1,1,0,1,0,1,1,0,0,1,0},
    {1,1,1,1,1,1,1,1,1,1,1,1,1,1,1,1}};

struct Masks { int m[16]; };
constexpr Masks make_masks() {
  Masks mk{};
  for (int j = 0; j < 16; ++j) {
    int m = 0;
    for (int i = 0; i < 5; ++i) m |= G5[i][j] << (4 - i);
    mk.m[j] = m;
  }
  return mk;
}
constexpr Masks mk = make_masks();

// Packed per-candidate word: bits 0..15 = odd-mask O(k), bit 16 = par2(k).
struct KW { unsigned w[32]; };
constexpr KW make_kw() {
  KW t{};
  for (int k = 0; k < 32; ++k) {
    unsigned om = 0, p2 = 0;
    for (int j = 0; j < 16; ++j) {
      int c = 0;
      for (int i = 0; i < 5; ++i) c += ((k >> (4 - i)) & 1) * G5[i][j];
      om |= (unsigned)(c & 1) << j;
      p2 ^= (unsigned)((c >> 1) & 1);
    }
    t.w[k] = om | (p2 << 16);
  }
  return t;
}
constexpr KW kwt = make_kw();

__device__ __forceinline__ int parity16i(const float (&f)[16]) {
  // exact: all addends are small integers
  float s0 = ((f[0] + f[1]) + (f[2] + f[3])) + ((f[4] + f[5]) + (f[6] + f[7]));
  float s1 = ((f[8] + f[9]) + (f[10] + f[11])) + ((f[12] + f[13]) + (f[14] + f[15]));
  return ((int)(s0 + s1)) & 1;
}

// Exact numpy-pipeline evaluation of candidate kk (R2..R12-verified).
template <bool EMIT>
__device__ __forceinline__ float eval_k(int kk, const float (&x)[16],
                                        const float (&xh)[16], float a,
                                        float (&y)[16]) {
#pragma clang fp contract(off)
  float f[16], dd[16];
#pragma unroll
  for (int j = 0; j < 16; ++j) {
    float c = (float)__builtin_popcount(kk & mk.m[j]);
    float x2 = __builtin_fmaf(c, -0.5f, xh[j]);  // == fl(xh - c/2)
    float fj = __builtin_rintf(x2);
    f[j] = fj;
    dd[j] = x2 - fj;                             // exact
  }
  const int par = parity16i(f);

  // first-occurrence argmax of |dd| -> onehot (left wins ties)
  float tv[16];
  int ti[16];
#pragma unroll
  for (int j = 0; j < 16; ++j) { tv[j] = __builtin_fabsf(dd[j]); ti[j] = 1 << j; }
#pragma unroll
  for (int w = 8; w >= 1; w >>= 1) {
#pragma unroll
    for (int j = 0; j < w; ++j) {
      bool L = tv[2 * j] >= tv[2 * j + 1];
      tv[j] = L ? tv[2 * j] : tv[2 * j + 1];
      ti[j] = L ? ti[2 * j] : ti[2 * j + 1];
    }
  }
  const int ohm = par ? ti[0] : 0;   // patch mask (0 when parity even)

  float sq[16];
#pragma unroll
  for (int j = 0; j < 16; ++j) {
    float c  = (float)__builtin_popcount(kk & mk.m[j]);
    float X  = __builtin_fmaf(2.0f, f[j], c);          // exact int
    float s2 = __builtin_copysignf(2.0f, dd[j]);       // corr direction
    float bitf = (float)((ohm >> j) & 1);
    float Xp = __builtin_fmaf(bitf, s2, X);            // exact int
    float e  = Xp - x[j];                              // single rounding
    sq[j] = e * e;
    if (EMIT) y[j] = Xp * a;
  }
  float r0 = sq[0] + sq[8],  r1 = sq[1] + sq[9];
  float r2 = sq[2] + sq[10], r3 = sq[3] + sq[11];
  float r4 = sq[4] + sq[12], r5 = sq[5] + sq[13];
  float r6 = sq[6] + sq[14], r7 = sq[7] + sq[15];
  return ((r0 + r1) + (r2 + r3)) + ((r4 + r5) + (r6 + r7));
}

__global__ __launch_bounds__(256, 4) void bw_quant_kernel(
    const float* __restrict__ x_in,
    const float* __restrict__ C_rep,   // unused (constexpr codebook)
    const float* __restrict__ a_ptr,
    float* __restrict__ y_out,
    int n_rows)
{
#pragma clang fp contract(off)
  __shared__ unsigned kw_lds[32];
  if (threadIdx.x < 32) kw_lds[threadIdx.x] = kwt.w[threadIdx.x];
  __syncthreads();

  const int gid = blockIdx.x * 256 + threadIdx.x;
  const int row = gid >> 1;
  const int half = gid & 1;        // which 16-candidate slice + which half-row store
  if (row >= n_rows) return;

  const float a = a_ptr[0];

  float x[16];
  {
    const float4* xr4 = reinterpret_cast<const float4*>(x_in + (size_t)row * 16);
#pragma unroll
    for (int q = 0; q < 4; ++q) {
      float4 v = xr4[q];
      x[q * 4 + 0] = v.x / a;
      x[q * 4 + 1] = v.y / a;
      x[q * 4 + 2] = v.z / a;
      x[q * 4 + 3] = v.w / a;
    }
  }

  // -------- mod-2 signed residual tables + parity masks (pass-1) ----------
  float dd0[16], dd1[16];
  int P0 = 0, P1 = 0;   // bit j = parity of rint(xh_j) / rint(xh_j - 0.5)
#pragma unroll
  for (int j = 0; j < 16; ++j) {
    float xh = x[j] * 0.5f;                 // exact
    float t0 = __builtin_rintf(xh);
    dd0[j] = xh - t0;
    float h  = xh - 0.5f;
    float t1 = __builtin_rintf(h);
    dd1[j] = h - t1;
    P0 |= ((int)t0 & 1) << j;
    P1 |= ((int)t1 & 1) << j;
  }

  // -------- pass 1: surrogate ranking over MY 16 candidates ---------------
  float b1 = __builtin_inff(), b2 = b1, b3 = b1;
  int k1 = 0, k2 = 0, k3 = 0;
  const int kbase = half << 4;

#pragma unroll 1
  for (int i = 0; i < 16; ++i) {
    const int k = kbase + i;
    const unsigned w = kw_lds[k];       // 2 distinct addrs/wave -> broadcast
    const unsigned O = w & 0xFFFFu;
    const int p2 = (int)(w >> 16);

    float d[16];
#pragma unroll
    for (int j = 0; j < 16; ++j)
      d[j] = ((O >> j) & 1u) ? dd1[j] : dd0[j];

    // ssum = sum d^2 : 4 parallel fma chains (surrogate precision)
    float s0 = __builtin_fmaf(d[0], d[0], __builtin_fmaf(d[1], d[1],
               __builtin_fmaf(d[2], d[2], d[3] * d[3])));
    float s1 = __builtin_fmaf(d[4], d[4], __builtin_fmaf(d[5], d[5],
               __builtin_fmaf(d[6], d[6], d[7] * d[7])));
    float s2 = __builtin_fmaf(d[8], d[8], __builtin_fmaf(d[9], d[9],
               __builtin_fmaf(d[10], d[10], d[11] * d[11])));
    float s3 = __builtin_fmaf(d[12], d[12], __builtin_fmaf(d[13], d[13],
               __builtin_fmaf(d[14], d[14], d[15] * d[15])));
    float s = (s0 + s1) + (s2 + s3);

    // mx = max |d| via v_max3 triples (abs folds as VOP3 src modifiers)
    float t0 = __builtin_fmaxf(__builtin_fmaxf(__builtin_fabsf(d[0]),  __builtin_fabsf(d[1])),  __builtin_fabsf(d[2]));
    float t1 = __builtin_fmaxf(__builtin_fmaxf(__builtin_fabsf(d[3]),  __builtin_fabsf(d[4])),  __builtin_fabsf(d[5]));
    float t2 = __builtin_fmaxf(__builtin_fmaxf(__builtin_fabsf(d[6]),  __builtin_fabsf(d[7])),  __builtin_fabsf(d[8]));
    float t3 = __builtin_fmaxf(__builtin_fmaxf(__builtin_fabsf(d[9]),  __builtin_fabsf(d[10])), __builtin_fabsf(d[11]));
    float t4 = __builtin_fmaxf(__builtin_fmaxf(__builtin_fabsf(d[12]), __builtin_fabsf(d[13])), __builtin_fabsf(d[14]));
    float mx = __builtin_fmaxf(__builtin_fmaxf(__builtin_fmaxf(t0, t1), t2),
                               __builtin_fmaxf(__builtin_fmaxf(t3, t4), __builtin_fabsf(d[15])));

    // mask parity (R5..R12-validated)
    unsigned sel = (O & (unsigned)P1) | (~O & (unsigned)P0);
    int cnt = __builtin_popcount(sel) + p2;
    float spen = s + __builtin_fmaf(-2.0f, mx, 1.0f);
    float dtil = (cnt & 1) ? spen : s;

    // stable top-3 insert (strict <: earlier k wins ties)
    bool lt1 = dtil < b1, lt2 = dtil < b2, lt3 = dtil < b3;
    float nb3 = lt3 ? (lt2 ? b2 : dtil) : b3;  int nk3 = lt3 ? (lt2 ? k2 : k) : k3;
    float nb2 = lt2 ? (lt1 ? b1 : dtil) : b2;  int nk2 = lt2 ? (lt1 ? k1 : k) : k2;
    b3 = nb3; k3 = nk3;
    b2 = nb2; k2 = nk2;
    b1 = lt1 ? dtil : b1;  k1 = lt1 ? k : k1;
  }

  // -------- merge the pair's top-3 lists (exact (dtil,k)-lex top-3) -------
  {
    float pb1 = __shfl_xor(b1, 1), pb2 = __shfl_xor(b2, 1), pb3 = __shfl_xor(b3, 1);
    int   pk1 = __shfl_xor(k1, 1), pk2 = __shfl_xor(k2, 1), pk3 = __shfl_xor(k3, 1);
    // lo list (k in [0,16)) as base; hi elements inserted with strict <
    // (all hi.k > all lo.k => strict < is exact lex merge, stable).
    float lb1 = half ? pb1 : b1, lb2 = half ? pb2 : b2, lb3 = half ? pb3 : b3;
    int   lk1 = half ? pk1 : k1, lk2 = half ? pk2 : k2, lk3 = half ? pk3 : k3;
    float hb1 = half ? b1 : pb1, hb2 = half ? b2 : pb2, hb3 = half ? b3 : pb3;
    int   hk1 = half ? k1 : pk1, hk2 = half ? k2 : pk2, hk3 = half ? k3 : pk3;

    b1 = lb1; b2 = lb2; b3 = lb3; k1 = lk1; k2 = lk2; k3 = lk3;
#pragma unroll
    for (int t = 0; t < 3; ++t) {
      float hv = (t == 0) ? hb1 : (t == 1) ? hb2 : hb3;
      int   hk = (t == 0) ? hk1 : (t == 1) ? hk2 : hk3;
      bool lt1_ = hv < b1, lt2_ = hv < b2, lt3_ = hv < b3;
      float nb3 = lt3_ ? (lt2_ ? b2 : hv) : b3;  int nk3 = lt3_ ? (lt2_ ? k2 : hk) : k3;
      float nb2 = lt2_ ? (lt1_ ? b1 : hv) : b2;  int nk2 = lt2_ ? (lt1_ ? k1 : hk) : k2;
      b3 = nb3; k3 = nk3;
      b2 = nb2; k2 = nk2;
      b1 = lt1_ ? hv : b1;  k1 = lt1_ ? hk : k1;
    }
  }

  // -------- pass 2: split exact evaluation (t0: k1, t1: k2, both: k3) -----
  float xh[16];
#pragma unroll
  for (int j = 0; j < 16; ++j) xh[j] = x[j] * 0.5f;   // exact

  float ydummy[16];
  const int kA = half ? k2 : k1;
  float DA = eval_k<false>(kA, x, xh, a, ydummy);
  float DB = eval_k<false>(k3, x, xh, a, ydummy);
  float DAp = __shfl_xor(DA, 1);
  float D1 = half ? DAp : DA;
  float D2 = half ? DA : DAp;
  float D3 = DB;

  // lexicographic (D, k) == numpy first-min over the candidate set
  bool c2 = (D2 < D1) || (D2 == D1 && k2 < k1);
  float Db = c2 ? D2 : D1;
  int kb = c2 ? k2 : k1;
  bool c3 = (D3 < Db) || (D3 == Db && k3 < kb);
  kb = c3 ? k3 : kb;

  // -------- emit: exact re-eval of the winner; store my half-row ----------
  float y[16];
  (void)eval_k<true>(kb, x, xh, a, y);

  float4 v0, v1;
  v0.x = half ? y[8]  : y[0];  v0.y = half ? y[9]  : y[1];
  v0.z = half ? y[10] : y[2];  v0.w = half ? y[11] : y[3];
  v1.x = half ? y[12] : y[4];  v1.y = half ? y[13] : y[5];
  v1.z = half ? y[14] : y[6];  v1.w = half ? y[15] : y[7];
  float4* dst = reinterpret_cast<float4*>(y_out + (size_t)row * 16 + half * 8);
  dst[0] = v0;
  dst[1] = v1;
}

extern "C" void kernel_launch(void* const* d_in, const int* in_sizes, int n_in,
                              void* d_out, int out_size, void* d_ws, size_t ws_size,
                              hipStream_t stream) {
  const float* x_in  = (const float*)d_in[0];
  const float* C_rep = (const float*)d_in[1];
  const float* a_ptr = (const float*)d_in[2];
  float* y_out = (float*)d_out;

  const int n_rows = in_sizes[0] / 16;
  const int block = 256;
  const int grid = (n_rows * 2 + block - 1) / block;
  bw_quant_kernel<<<grid, block, 0, stream>>>(x_in, C_rep, a_ptr, y_out, n_rows);
}

// Round 14
// 23.821 us; speedup vs baseline: 1.9101x; 1.8545x over previous
//
#include <hip/hip_runtime.h>

// Barnes-Wall Lambda16 quantizer — R11 base + butterfly max-DP + PAR32.
// (Both grafts are semantically validated: R12 passed absmax 0.0; its
// regression was register spill from the OTHER changes (LDS xh stash,
// merged-emit live arrays). This round keeps R11's register envelope.)
//
// Pass 1 (surrogate, fully unrolled, zero memory ops, ~10 ops/candidate):
//   RM(1,4): O(k)_j = k0 XOR <kappa, pt_j>, kappa = k>>1, pt bijective.
//   ssum: WHT (R11-validated): s = k0 ? S1 - h[kappa] : S0 + h[kappa].
//   mx(k): butterfly max-DP on (T,S) by point (R12-validated):
//     stage s: T[p],T[p|s],S[p],S[p|s] <- max(T,T'),max(T,S'),max(S,S'),
//     max(S,T'); then mx(2kap)=T[kap], mx(2kap+1)=S[kap]. f32 max is
//     assoc/comm => bit-identical to the per-k tree (same multiset).
//   parity: PAR32 word (R12-validated GF2 rewrite of the R5..R13 popcount
//     formula), bit k = surrogate parity of candidate k; per-k = shift+and.
//   Dtil = s + par*(1-2mx); stable top-3 (strict <, earlier k wins ties).
//
// Pass 2 (bit-exact numpy pipeline, R2..R13-verified, == R11 verbatim):
//   reload x + re-divide (identical fl ops -> identical bits; L2-hot);
//   eval_k reads codeword row from LDS (4x ds_read_b128); 3 evals +
//   lexicographic (D,k) == numpy first-min; separate emit re-eval.
//
// Pass-2 bit-exactness invariants (absmax must be 0.0):
//  - fp contract OFF; fmaf only where exact or single-rounding-identical:
//    fmaf(c,-0.5,xh) == fl(xh-c/2); fmaf(2,f,c) exact; Xp=fmaf(bit,+-2,X)
//    exact; e = fmaf(-2,xh,Xp) == fl(Xp-x) single rounding (x=2*xh exact).
//  - rintf == round-half-to-even == np.round; dd = x2 - f exact.
//  - first-max: contiguous-pair tournament, left wins ties (>=).
//  - parity (pass-2): float sum-tree of integer-valued f (exact), cvt, &1.
//  - D in numpy's n=16 pairwise order:
//    r[j]=sq[j]+sq[j+8]; D=((r0+r1)+(r2+r3))+((r4+r5)+(r6+r7)).
//
// Register discipline (allocator rule confirmed R3/R9/R13: (256,N) targets
// ~256/N VGPRs): pass-1 persistent = T[16]+S[16]+h[16]+S0,S1+PAR+top3 ~ 57
// == R11's envelope (T/S replace dd0/dd1 in place). Gates: VGPR=64,
// FETCH ~ 8.3 MB, WRITE ~ 16.4 MB.

constexpr int G5[5][16] = {
    {1,1,1,1,0,1,0,1,1,0,0,1,0,0,0,0},
    {0,1,1,1,1,0,1,0,1,1,0,0,1,0,0,0},
    {0,0,1,1,1,1,0,1,0,1,1,0,0,1,0,0},
    {0,0,0,1,1,1,1,0,1,0,1,1,0,0,1,0},
    {1,1,1,1,1,1,1,1,1,1,1,1,1,1,1,1}};

struct Tabs {
  int m[16];        // column bit-masks: c_j(k) = popcount(k & m[j])
  int pt[16];       // pt[j] = 4-bit point (rows 0..3 at column j), bijective
  unsigned rowm[5]; // Row_i as bitmask over j
  unsigned par2w;   // bit k = par2(k) = XOR_j (c_j(k)>>1)&1
};
constexpr Tabs make_tabs() {
  Tabs t{};
  for (int j = 0; j < 16; ++j) {
    int m = 0;
    for (int i = 0; i < 5; ++i) m |= G5[i][j] << (4 - i);
    t.m[j] = m;
    t.pt[j] = (G5[0][j] << 3) | (G5[1][j] << 2) | (G5[2][j] << 1) | G5[3][j];
  }
  for (int i = 0; i < 5; ++i) {
    unsigned rm = 0;
    for (int j = 0; j < 16; ++j) rm |= (unsigned)G5[i][j] << j;
    t.rowm[i] = rm;
  }
  t.par2w = 0;
  for (int k = 0; k < 32; ++k) {
    unsigned p2 = 0;
    for (int j = 0; j < 16; ++j) {
      int c = 0;
      for (int i = 0; i < 5; ++i) c += ((k >> (4 - i)) & 1) * G5[i][j];
      p2 ^= (unsigned)((c >> 1) & 1);
    }
    t.par2w |= p2 << k;
  }
  return t;
}
constexpr Tabs tb = make_tabs();

__device__ __forceinline__ int parity16i(const float (&f)[16]) {
  // exact: all addends are small integers
  float s0 = ((f[0] + f[1]) + (f[2] + f[3])) + ((f[4] + f[5]) + (f[6] + f[7]));
  float s1 = ((f[8] + f[9]) + (f[10] + f[11])) + ((f[12] + f[13]) + (f[14] + f[15]));
  return ((int)(s0 + s1)) & 1;
}

// Exact numpy-pipeline evaluation of candidate kk (R2..R13-verified).
// Codeword row from LDS.
template <bool EMIT>
__device__ __forceinline__ float eval_k(int kk, const float (&xh)[16], float a,
                                        float (&y)[16], const float (*Cs)[16]) {
#pragma clang fp contract(off)
  float cf[16];
  {
    const float4* crow = reinterpret_cast<const float4*>(&Cs[kk][0]);
    float4 c0 = crow[0], c1 = crow[1], c2 = crow[2], c3 = crow[3];
    cf[0] = c0.x; cf[1] = c0.y; cf[2] = c0.z; cf[3] = c0.w;
    cf[4] = c1.x; cf[5] = c1.y; cf[6] = c1.z; cf[7] = c1.w;
    cf[8] = c2.x; cf[9] = c2.y; cf[10] = c2.z; cf[11] = c2.w;
    cf[12] = c3.x; cf[13] = c3.y; cf[14] = c3.z; cf[15] = c3.w;
  }
  float f[16], dd[16];
#pragma unroll
  for (int j = 0; j < 16; ++j) {
    float x2 = __builtin_fmaf(cf[j], -0.5f, xh[j]);  // == fl(xh - c/2)
    float fj = __builtin_rintf(x2);
    f[j] = fj;
    dd[j] = x2 - fj;                                 // exact
  }
  const int par = parity16i(f);

  // first-occurrence argmax of |dd| -> onehot (left wins ties)
  float tv[16];
  int ti[16];
#pragma unroll
  for (int j = 0; j < 16; ++j) { tv[j] = __builtin_fabsf(dd[j]); ti[j] = 1 << j; }
#pragma unroll
  for (int w = 8; w >= 1; w >>= 1) {
#pragma unroll
    for (int j = 0; j < w; ++j) {
      bool L = tv[2 * j] >= tv[2 * j + 1];
      tv[j] = L ? tv[2 * j] : tv[2 * j + 1];
      ti[j] = L ? ti[2 * j] : ti[2 * j + 1];
    }
  }
  const int ohm = par ? ti[0] : 0;   // patch mask (0 when parity even)

  float sq[16];
#pragma unroll
  for (int j = 0; j < 16; ++j) {
    float X  = __builtin_fmaf(2.0f, f[j], cf[j]);      // exact int
    float s2 = __builtin_copysignf(2.0f, dd[j]);       // corr direction
    float bitf = (float)((ohm >> j) & 1);
    float Xp = __builtin_fmaf(bitf, s2, X);            // exact int
    float e  = __builtin_fmaf(-2.0f, xh[j], Xp);       // == fl(Xp - x)
    sq[j] = e * e;
    if (EMIT) y[j] = Xp * a;
  }
  float r0 = sq[0] + sq[8],  r1 = sq[1] + sq[9];
  float r2 = sq[2] + sq[10], r3 = sq[3] + sq[11];
  float r4 = sq[4] + sq[12], r5 = sq[5] + sq[13];
  float r6 = sq[6] + sq[14], r7 = sq[7] + sq[15];
  return ((r0 + r1) + (r2 + r3)) + ((r4 + r5) + (r6 + r7));
}

__global__ __launch_bounds__(256, 4) void bw_quant_kernel(
    const float* __restrict__ x_in,
    const float* __restrict__ C_rep,   // unused (constexpr codebook)
    const float* __restrict__ a_ptr,
    float* __restrict__ y_out,
    int n_rows)
{
#pragma clang fp contract(off)
  __shared__ alignas(16) float Cs[32][16];
  for (int i = threadIdx.x; i < 32 * 16; i += 256)
    Cs[i >> 4][i & 15] = (float)__builtin_popcount((i >> 4) & tb.m[i & 15]);
  __syncthreads();

  const int row = blockIdx.x * 256 + threadIdx.x;
  if (row >= n_rows) return;

  const float a = a_ptr[0];

  // -------- prologue: residuals -> T/S/g/sq0 by point, parity masks -------
  float g[16], sq0[16], T[16], S[16];
  int P0 = 0, P1 = 0;
  {
    const float4* xr4 = reinterpret_cast<const float4*>(x_in + (size_t)row * 16);
    float xv[16];
#pragma unroll
    for (int q = 0; q < 4; ++q) {
      float4 v = xr4[q];
      xv[q * 4 + 0] = v.x; xv[q * 4 + 1] = v.y;
      xv[q * 4 + 2] = v.z; xv[q * 4 + 3] = v.w;
    }
#pragma unroll
    for (int j = 0; j < 16; ++j) {
      float xj = xv[j] / a;
      float xh = xj * 0.5f;                 // exact
      float t0 = __builtin_rintf(xh);
      float d0 = xh - t0;                   // exact
      float hm = xh - 0.5f;
      float t1 = __builtin_rintf(hm);
      float d1 = hm - t1;                   // exact
      P0 |= ((int)t0 & 1) << j;
      P1 |= ((int)t1 & 1) << j;
      sq0[j] = d0 * d0;
      g[tb.pt[j]] = __builtin_fmaf(d1, d1, -sq0[j]);  // delta by point
      T[tb.pt[j]] = __builtin_fabsf(d0);              // u by point
      S[tb.pt[j]] = __builtin_fabsf(d1);              // w by point
    }
  }
  float S0 = (((sq0[0] + sq0[1]) + (sq0[2] + sq0[3])) + ((sq0[4] + sq0[5]) + (sq0[6] + sq0[7])))
           + (((sq0[8] + sq0[9]) + (sq0[10] + sq0[11])) + ((sq0[12] + sq0[13]) + (sq0[14] + sq0[15])));

  // fast WHT on g (ssum path, R11-validated)
#pragma unroll
  for (int st = 1; st < 16; st <<= 1) {
#pragma unroll
    for (int p = 0; p < 16; ++p) {
      if (!(p & st)) {
        float u = g[p], v = g[p | st];
        g[p] = u + v;
        g[p | st] = u - v;
      }
    }
  }
  float S1 = S0 + g[0];
  float h[16];
  h[0] = 0.0f;
#pragma unroll
  for (int t = 1; t < 16; ++t) h[t] = 0.5f * (g[0] - g[t]);

  // butterfly max-DP (R12-validated): T[kap]=mx(2kap), S[kap]=mx(2kap+1)
#pragma unroll
  for (int st = 1; st < 16; st <<= 1) {
#pragma unroll
    for (int p = 0; p < 16; ++p) {
      if (!(p & st)) {
        float tA = T[p], tB = T[p | st];
        float sA = S[p], sB = S[p | st];
        T[p]      = __builtin_fmaxf(tA, tB);
        T[p | st] = __builtin_fmaxf(tA, sB);
        S[p]      = __builtin_fmaxf(sA, sB);
        S[p | st] = __builtin_fmaxf(sA, tB);
      }
    }
  }

  // PAR32 (R12-validated): bit k = surrogate parity of candidate k
  unsigned PAR;
  {
    unsigned Q = (unsigned)(P0 ^ P1);
    PAR = ((__builtin_popcount((unsigned)P0) & 1) ? 0xFFFFFFFFu : 0u) ^ tb.par2w;
    PAR ^= ((__builtin_popcount(Q & tb.rowm[0]) & 1) ? 0xFFFF0000u : 0u);  // k bit 4
    PAR ^= ((__builtin_popcount(Q & tb.rowm[1]) & 1) ? 0xFF00FF00u : 0u);  // k bit 3
    PAR ^= ((__builtin_popcount(Q & tb.rowm[2]) & 1) ? 0xF0F0F0F0u : 0u);  // k bit 2
    PAR ^= ((__builtin_popcount(Q & tb.rowm[3]) & 1) ? 0xCCCCCCCCu : 0u);  // k bit 1
    PAR ^= ((__builtin_popcount(Q & tb.rowm[4]) & 1) ? 0xAAAAAAAAu : 0u);  // k bit 0
  }

  // -------- pass 1: fully unrolled surrogate ranking, stable top-3 --------
  float b1 = __builtin_inff(), b2 = b1, b3 = b1;
  int k1 = 0, k2 = 0, k3 = 0;

#pragma unroll
  for (int k = 0; k < 32; ++k) {
    const int kap = k >> 1;
    float s  = (k & 1) ? (S1 - h[kap]) : (S0 + h[kap]);   // WHT ssum
    float mx = (k & 1) ? S[kap] : T[kap];                 // DP max (register)
    float spen = s + __builtin_fmaf(-2.0f, mx, 1.0f);
    float dtil = ((PAR >> k) & 1u) ? spen : s;

    // stable top-3 insert (strict <: earlier k wins ties)
    bool lt1 = dtil < b1, lt2 = dtil < b2, lt3 = dtil < b3;
    float nb3 = lt3 ? (lt2 ? b2 : dtil) : b3;  int nk3 = lt3 ? (lt2 ? k2 : k) : k3;
    float nb2 = lt2 ? (lt1 ? b1 : dtil) : b2;  int nk2 = lt2 ? (lt1 ? k1 : k) : k2;
    b3 = nb3; k3 = nk3;
    b2 = nb2; k2 = nk2;
    b1 = lt1 ? dtil : b1;  k1 = lt1 ? k : k1;
  }

  // -------- pass 2: reload x (identical fl ops), exact evals (R11) --------
  float xh[16];
  {
    const float4* xr4 = reinterpret_cast<const float4*>(x_in + (size_t)row * 16);
#pragma unroll
    for (int q = 0; q < 4; ++q) {
      float4 v = xr4[q];
      xh[q * 4 + 0] = (v.x / a) * 0.5f;
      xh[q * 4 + 1] = (v.y / a) * 0.5f;
      xh[q * 4 + 2] = (v.z / a) * 0.5f;
      xh[q * 4 + 3] = (v.w / a) * 0.5f;
    }
  }

  float ydummy[16];
  float D1 = eval_k<false>(k1, xh, a, ydummy, Cs);
  float D2 = eval_k<false>(k2, xh, a, ydummy, Cs);
  float D3 = eval_k<false>(k3, xh, a, ydummy, Cs);

  // lexicographic (D, k) == numpy first-min over the candidate set
  bool c2 = (D2 < D1) || (D2 == D1 && k2 < k1);
  float Db = c2 ? D2 : D1;
  int kb = c2 ? k2 : k1;
  bool c3 = (D3 < Db) || (D3 == Db && k3 < kb);
  kb = c3 ? k3 : kb;

  // -------- emit: exact re-eval of the winner -----------------------------
  float y[16];
  (void)eval_k<true>(kb, xh, a, y, Cs);

  float4* yr4 = reinterpret_cast<float4*>(y_out + (size_t)row * 16);
#pragma unroll
  for (int q = 0; q < 4; ++q) {
    float4 v;
    v.x = y[q * 4 + 0]; v.y = y[q * 4 + 1];
    v.z = y[q * 4 + 2]; v.w = y[q * 4 + 3];
    yr4[q] = v;
  }
}

extern "C" void kernel_launch(void* const* d_in, const int* in_sizes, int n_in,
                              void* d_out, int out_size, void* d_ws, size_t ws_size,
                              hipStream_t stream) {
  const float* x_in  = (const float*)d_in[0];
  const float* C_rep = (const float*)d_in[1];
  const float* a_ptr = (const float*)d_in[2];
  float* y_out = (float*)d_out;

  const int n_rows = in_sizes[0] / 16;
  const int block = 256;
  const int grid = (n_rows + block - 1) / block;
  bw_quant_kernel<<<grid, block, 0, stream>>>(x_in, C_rep, a_ptr, y_out, n_rows);
}

// Round 15
// 23.456 us; speedup vs baseline: 1.9398x; 1.0156x over previous
//
#include <hip/hip_runtime.h>

// Barnes-Wall Lambda16 quantizer — R14 + launch_bounds(256,2) headroom:
// xh kept in registers (no pass-2 reload) + merged-emit pass-2 (3 evals).
//
// Occupancy arithmetic: grid = 1024 blocks / 256 CUs caps residency at
// 4 waves/SIMD no matter what; 4 waves/SIMD is achievable for any VGPR
// <= 128 (512/128=4). So raising the allocator target from 64 (256,4) to
// 128 (256,2) is FREE occupancy-wise and removes the 64-reg squeeze that
// forced R11/R14's reload+re-divide and separate emit eval.
// (Allocator rule confirmed R3/R9/R13: (256,N) targets ~256/N VGPRs.)
//
// Pass 1 (surrogate, fully unrolled, zero memory ops — R14-validated):
//   ssum: WHT — s = k0 ? S1 - h[kappa] : S0 + h[kappa]  (R11/R14)
//   mx:   butterfly max-DP — mx(2kap)=T[kap], mx(2kap+1)=S[kap]  (R12/R14)
//   par:  PAR32 word, per-k shift+and  (R12/R14)
//   Dtil = s + par*(1-2mx); stable top-3 (strict <, earlier k wins ties).
//
// Pass 2 (bit-exact numpy pipeline, R2..R14-verified; merged emit per R12):
//   3 eval_k calls (each emits y = Xp*a); running winner by lexicographic
//   (D,k) == numpy first-min, y selected via cndmask.
//
// Pass-2 bit-exactness invariants (absmax must be 0.0):
//  - fp contract OFF; fmaf only where exact or single-rounding-identical:
//    fmaf(c,-0.5,xh) == fl(xh-c/2); fmaf(2,f,c) exact; Xp=fmaf(bit,+-2,X)
//    exact; e = fmaf(-2,xh,Xp) == fl(Xp-x) single rounding (x=2*xh exact).
//  - rintf == round-half-to-even == np.round; dd = x2 - f exact.
//  - first-max: contiguous-pair tournament, left wins ties (>=).
//  - parity (pass-2): float sum-tree of integer-valued f (exact), cvt, &1.
//  - D in numpy's n=16 pairwise order:
//    r[j]=sq[j]+sq[j+8]; D=((r0+r1)+(r2+r3))+((r4+r5)+(r6+r7)).
//
// Register budget: pass-1 live = xh(16)+T,S(32)+h(16)+S0,S1,PAR+top3 ~ 73;
// pass-2 peak = xh(16)+yb(16)+yt(16)+eval internals(~40) ~ 100. Both < 128.
// Gates: VGPR 84-120, FETCH ~ 8.3 MB, WRITE ~ 16.4 MB (no scratch).

constexpr int G5[5][16] = {
    {1,1,1,1,0,1,0,1,1,0,0,1,0,0,0,0},
    {0,1,1,1,1,0,1,0,1,1,0,0,1,0,0,0},
    {0,0,1,1,1,1,0,1,0,1,1,0,0,1,0,0},
    {0,0,0,1,1,1,1,0,1,0,1,1,0,0,1,0},
    {1,1,1,1,1,1,1,1,1,1,1,1,1,1,1,1}};

struct Tabs {
  int m[16];        // column bit-masks: c_j(k) = popcount(k & m[j])
  int pt[16];       // pt[j] = 4-bit point (rows 0..3 at column j), bijective
  unsigned rowm[5]; // Row_i as bitmask over j
  unsigned par2w;   // bit k = par2(k) = XOR_j (c_j(k)>>1)&1
};
constexpr Tabs make_tabs() {
  Tabs t{};
  for (int j = 0; j < 16; ++j) {
    int m = 0;
    for (int i = 0; i < 5; ++i) m |= G5[i][j] << (4 - i);
    t.m[j] = m;
    t.pt[j] = (G5[0][j] << 3) | (G5[1][j] << 2) | (G5[2][j] << 1) | G5[3][j];
  }
  for (int i = 0; i < 5; ++i) {
    unsigned rm = 0;
    for (int j = 0; j < 16; ++j) rm |= (unsigned)G5[i][j] << j;
    t.rowm[i] = rm;
  }
  t.par2w = 0;
  for (int k = 0; k < 32; ++k) {
    unsigned p2 = 0;
    for (int j = 0; j < 16; ++j) {
      int c = 0;
      for (int i = 0; i < 5; ++i) c += ((k >> (4 - i)) & 1) * G5[i][j];
      p2 ^= (unsigned)((c >> 1) & 1);
    }
    t.par2w |= p2 << k;
  }
  return t;
}
constexpr Tabs tb = make_tabs();

__device__ __forceinline__ int parity16i(const float (&f)[16]) {
  // exact: all addends are small integers
  float s0 = ((f[0] + f[1]) + (f[2] + f[3])) + ((f[4] + f[5]) + (f[6] + f[7]));
  float s1 = ((f[8] + f[9]) + (f[10] + f[11])) + ((f[12] + f[13]) + (f[14] + f[15]));
  return ((int)(s0 + s1)) & 1;
}

// Exact numpy-pipeline evaluation of candidate kk (R2..R14-verified).
// Codeword row from LDS; always emits y (scaled candidate).
__device__ __forceinline__ float eval_k(int kk, const float (&xh)[16], float a,
                                        float (&y)[16], const float (*Cs)[16]) {
#pragma clang fp contract(off)
  float cf[16];
  {
    const float4* crow = reinterpret_cast<const float4*>(&Cs[kk][0]);
    float4 c0 = crow[0], c1 = crow[1], c2 = crow[2], c3 = crow[3];
    cf[0] = c0.x; cf[1] = c0.y; cf[2] = c0.z; cf[3] = c0.w;
    cf[4] = c1.x; cf[5] = c1.y; cf[6] = c1.z; cf[7] = c1.w;
    cf[8] = c2.x; cf[9] = c2.y; cf[10] = c2.z; cf[11] = c2.w;
    cf[12] = c3.x; cf[13] = c3.y; cf[14] = c3.z; cf[15] = c3.w;
  }
  float f[16], dd[16];
#pragma unroll
  for (int j = 0; j < 16; ++j) {
    float x2 = __builtin_fmaf(cf[j], -0.5f, xh[j]);  // == fl(xh - c/2)
    float fj = __builtin_rintf(x2);
    f[j] = fj;
    dd[j] = x2 - fj;                                 // exact
  }
  const int par = parity16i(f);

  // first-occurrence argmax of |dd| -> onehot (left wins ties)
  float tv[16];
  int ti[16];
#pragma unroll
  for (int j = 0; j < 16; ++j) { tv[j] = __builtin_fabsf(dd[j]); ti[j] = 1 << j; }
#pragma unroll
  for (int w = 8; w >= 1; w >>= 1) {
#pragma unroll
    for (int j = 0; j < w; ++j) {
      bool L = tv[2 * j] >= tv[2 * j + 1];
      tv[j] = L ? tv[2 * j] : tv[2 * j + 1];
      ti[j] = L ? ti[2 * j] : ti[2 * j + 1];
    }
  }
  const int ohm = par ? ti[0] : 0;   // patch mask (0 when parity even)

  float sq[16];
#pragma unroll
  for (int j = 0; j < 16; ++j) {
    float X  = __builtin_fmaf(2.0f, f[j], cf[j]);      // exact int
    float s2 = __builtin_copysignf(2.0f, dd[j]);       // corr direction
    float bitf = (float)((ohm >> j) & 1);
    float Xp = __builtin_fmaf(bitf, s2, X);            // exact int
    float e  = __builtin_fmaf(-2.0f, xh[j], Xp);       // == fl(Xp - x)
    sq[j] = e * e;
    y[j] = Xp * a;
  }
  float r0 = sq[0] + sq[8],  r1 = sq[1] + sq[9];
  float r2 = sq[2] + sq[10], r3 = sq[3] + sq[11];
  float r4 = sq[4] + sq[12], r5 = sq[5] + sq[13];
  float r6 = sq[6] + sq[14], r7 = sq[7] + sq[15];
  return ((r0 + r1) + (r2 + r3)) + ((r4 + r5) + (r6 + r7));
}

__global__ __launch_bounds__(256, 2) void bw_quant_kernel(
    const float* __restrict__ x_in,
    const float* __restrict__ C_rep,   // unused (constexpr codebook)
    const float* __restrict__ a_ptr,
    float* __restrict__ y_out,
    int n_rows)
{
#pragma clang fp contract(off)
  __shared__ alignas(16) float Cs[32][16];
  for (int i = threadIdx.x; i < 32 * 16; i += 256)
    Cs[i >> 4][i & 15] = (float)__builtin_popcount((i >> 4) & tb.m[i & 15]);
  __syncthreads();

  const int row = blockIdx.x * 256 + threadIdx.x;
  if (row >= n_rows) return;

  const float a = a_ptr[0];

  // -------- prologue: xh + residuals -> T/S/g/sq0 by point, parity masks --
  float xh[16], g[16], sq0[16], T[16], S[16];
  int P0 = 0, P1 = 0;
  {
    const float4* xr4 = reinterpret_cast<const float4*>(x_in + (size_t)row * 16);
    float xv[16];
#pragma unroll
    for (int q = 0; q < 4; ++q) {
      float4 v = xr4[q];
      xv[q * 4 + 0] = v.x; xv[q * 4 + 1] = v.y;
      xv[q * 4 + 2] = v.z; xv[q * 4 + 3] = v.w;
    }
#pragma unroll
    for (int j = 0; j < 16; ++j) {
      float xj = xv[j] / a;
      float xhj = xj * 0.5f;                // exact
      xh[j] = xhj;                          // live through both passes
      float t0 = __builtin_rintf(xhj);
      float d0 = xhj - t0;                  // exact
      float hm = xhj - 0.5f;
      float t1 = __builtin_rintf(hm);
      float d1 = hm - t1;                   // exact
      P0 |= ((int)t0 & 1) << j;
      P1 |= ((int)t1 & 1) << j;
      sq0[j] = d0 * d0;
      g[tb.pt[j]] = __builtin_fmaf(d1, d1, -sq0[j]);  // delta by point
      T[tb.pt[j]] = __builtin_fabsf(d0);              // u by point
      S[tb.pt[j]] = __builtin_fabsf(d1);              // w by point
    }
  }
  float S0 = (((sq0[0] + sq0[1]) + (sq0[2] + sq0[3])) + ((sq0[4] + sq0[5]) + (sq0[6] + sq0[7])))
           + (((sq0[8] + sq0[9]) + (sq0[10] + sq0[11])) + ((sq0[12] + sq0[13]) + (sq0[14] + sq0[15])));

  // fast WHT on g (ssum path, R11/R14-validated)
#pragma unroll
  for (int st = 1; st < 16; st <<= 1) {
#pragma unroll
    for (int p = 0; p < 16; ++p) {
      if (!(p & st)) {
        float u = g[p], v = g[p | st];
        g[p] = u + v;
        g[p | st] = u - v;
      }
    }
  }
  float S1 = S0 + g[0];
  float h[16];
  h[0] = 0.0f;
#pragma unroll
  for (int t = 1; t < 16; ++t) h[t] = 0.5f * (g[0] - g[t]);

  // butterfly max-DP (R12/R14-validated): T[kap]=mx(2kap), S[kap]=mx(2kap+1)
#pragma unroll
  for (int st = 1; st < 16; st <<= 1) {
#pragma unroll
    for (int p = 0; p < 16; ++p) {
      if (!(p & st)) {
        float tA = T[p], tB = T[p | st];
        float sA = S[p], sB = S[p | st];
        T[p]      = __builtin_fmaxf(tA, tB);
        T[p | st] = __builtin_fmaxf(tA, sB);
        S[p]      = __builtin_fmaxf(sA, sB);
        S[p | st] = __builtin_fmaxf(sA, tB);
      }
    }
  }

  // PAR32 (R12/R14-validated): bit k = surrogate parity of candidate k
  unsigned PAR;
  {
    unsigned Q = (unsigned)(P0 ^ P1);
    PAR = ((__builtin_popcount((unsigned)P0) & 1) ? 0xFFFFFFFFu : 0u) ^ tb.par2w;
    PAR ^= ((__builtin_popcount(Q & tb.rowm[0]) & 1) ? 0xFFFF0000u : 0u);  // k bit 4
    PAR ^= ((__builtin_popcount(Q & tb.rowm[1]) & 1) ? 0xFF00FF00u : 0u);  // k bit 3
    PAR ^= ((__builtin_popcount(Q & tb.rowm[2]) & 1) ? 0xF0F0F0F0u : 0u);  // k bit 2
    PAR ^= ((__builtin_popcount(Q & tb.rowm[3]) & 1) ? 0xCCCCCCCCu : 0u);  // k bit 1
    PAR ^= ((__builtin_popcount(Q & tb.rowm[4]) & 1) ? 0xAAAAAAAAu : 0u);  // k bit 0
  }

  // -------- pass 1: fully unrolled surrogate ranking, stable top-3 --------
  float b1 = __builtin_inff(), b2 = b1, b3 = b1;
  int k1 = 0, k2 = 0, k3 = 0;

#pragma unroll
  for (int k = 0; k < 32; ++k) {
    const int kap = k >> 1;
    float s  = (k & 1) ? (S1 - h[kap]) : (S0 + h[kap]);   // WHT ssum
    float mx = (k & 1) ? S[kap] : T[kap];                 // DP max (register)
    float spen = s + __builtin_fmaf(-2.0f, mx, 1.0f);
    float dtil = ((PAR >> k) & 1u) ? spen : s;

    // stable top-3 insert (strict <: earlier k wins ties)
    bool lt1 = dtil < b1, lt2 = dtil < b2, lt3 = dtil < b3;
    float nb3 = lt3 ? (lt2 ? b2 : dtil) : b3;  int nk3 = lt3 ? (lt2 ? k2 : k) : k3;
    float nb2 = lt2 ? (lt1 ? b1 : dtil) : b2;  int nk2 = lt2 ? (lt1 ? k1 : k) : k2;
    b3 = nb3; k3 = nk3;
    b2 = nb2; k2 = nk2;
    b1 = lt1 ? dtil : b1;  k1 = lt1 ? k : k1;
  }

  // -------- pass 2: exact evals with running winner (merged emit) ---------
  float yb[16], yt[16];
  float Db = eval_k(k1, xh, a, yb, Cs);
  int kb = k1;
  {
    float D2 = eval_k(k2, xh, a, yt, Cs);
    bool c2 = (D2 < Db) || (D2 == Db && k2 < kb);
    Db = c2 ? D2 : Db; kb = c2 ? k2 : kb;
#pragma unroll
    for (int j = 0; j < 16; ++j) yb[j] = c2 ? yt[j] : yb[j];
  }
  {
    float D3 = eval_k(k3, xh, a, yt, Cs);
    bool c3 = (D3 < Db) || (D3 == Db && k3 < kb);
#pragma unroll
    for (int j = 0; j < 16; ++j) yb[j] = c3 ? yt[j] : yb[j];
  }

  float4* yr4 = reinterpret_cast<float4*>(y_out + (size_t)row * 16);
#pragma unroll
  for (int q = 0; q < 4; ++q) {
    float4 v;
    v.x = yb[q * 4 + 0]; v.y = yb[q * 4 + 1];
    v.z = yb[q * 4 + 2]; v.w = yb[q * 4 + 3];
    yr4[q] = v;
  }
}

extern "C" void kernel_launch(void* const* d_in, const int* in_sizes, int n_in,
                              void* d_out, int out_size, void* d_ws, size_t ws_size,
                              hipStream_t stream) {
  const float* x_in  = (const float*)d_in[0];
  const float* C_rep = (const float*)d_in[1];
  const float* a_ptr = (const float*)d_in[2];
  float* y_out = (float*)d_out;

  const int n_rows = in_sizes[0] / 16;
  const int block = 256;
  const int grid = (n_rows + block - 1) / block;
  bw_quant_kernel<<<grid, block, 0, stream>>>(x_in, C_rep, a_ptr, y_out, n_rows);
}